// Round 11
// baseline (156.961 us; speedup 1.0000x reference)
//
#include <hip/hip_runtime.h>
#include <hip/hip_bf16.h>
#include <math.h>

// TriangleAttention — round 17: k3 audit fix. k3 needs ~80-85 VGPRs (bfr 32 +
// acc 32 + temps) but carried __launch_bounds__(256,4) — the same bound that
// empirically clamps the allocator to 64 VGPRs (r7: clamped kernel spilled
// ~700 MB). k3 has likely been spilling ~20 regs/thread all session, invisible
// because its counters never made top-5. Fix: (256,2) (cap ~128). Also k3
// decode bl=b&511 so its block lands on XCD bl%8 — same XCD where the 4 ka
// head-blocks wrote GO -> GO reads are L2 hits (same mechanism that cut ka's
// FETCH 8x in r16). ka/k0 untouched (ka counters = session-noise reference).
// HAZARD RULES (r10-r14): inline asm never reads an MFMA dest directly — a
// compiler VALU op in between (s*L2E mul / ag+bg add) absorbs wait-states.
// BAN LIST (r7-8): __builtin_amdgcn_exp2f/rcpf (phantom scratch traffic).
// CANARY: absmax exactly 0.0078125, ka FETCH ~8.5 MB / WRITE ~16.4 MB /
// VGPR 52 unchanged.
// B=2, L=256, D=64, H=4, Dh=16.
// k0: LN once per row -> bf16 zn in first half of `out` (k3 overwrites all).
// ka: grid 2048 (bl=g&511, h=g>>9 -> same-bl heads share XCD L2); 16x16x16
//     attention, Q/P in registers; l = ones@P on matrix pipe; 18.7 KB LDS.
// k3: out = sum_h GO_h @ Wo_h^T + bo; grid 1024 (bl=b&511, half=b>>9);
//     operand-swapped MFMA -> f32x4 stores.
//
// 16x16x32 layouts (verified r2-5):  A[m=lane&15][k=quad*8+u],
//   B[k=quad*8+u][n=lane&15], C/D: col=lane&15, row=quad*4+reg.
// 16x16x16 layouts (verified r14): A[m=lane&15][k=quad*4+u],
//   B[k=quad*4+u][n=lane&15], C/D identical to above.

typedef __attribute__((ext_vector_type(4))) float f32x4;
typedef __attribute__((ext_vector_type(8))) short s16x8;
typedef __attribute__((ext_vector_type(4))) short s16x4;

#define MFMA16(a, b, c) __builtin_amdgcn_mfma_f32_16x16x32_bf16((a), (b), (c), 0, 0, 0)

__device__ __forceinline__ f32x4 mfma16b(s16x4 a, s16x4 b, f32x4 c) {
#if __has_builtin(__builtin_amdgcn_mfma_f32_16x16x16bf16_1k)
    return __builtin_amdgcn_mfma_f32_16x16x16bf16_1k(a, b, c, 0, 0, 0);
#elif __has_builtin(__builtin_amdgcn_mfma_f32_16x16x16_bf16)
    return __builtin_amdgcn_mfma_f32_16x16x16_bf16(a, b, c, 0, 0, 0);
#else
    f32x4 d;
    asm volatile("s_nop 1\n\t"
                 "v_mfma_f32_16x16x16_bf16 %0, %1, %2, %3\n\t"
                 "s_nop 7\n\t"
                 "s_nop 7"
                 : "=v"(d) : "v"(a), "v"(b), "v"(c));
    return d;
#endif
}

__device__ __forceinline__ float exp2a(float x) {   // raw v_exp_f32 (input MUST
    float r;                                        // be VALU-produced, not MFMA)
    asm("v_exp_f32 %0, %1" : "=v"(r) : "v"(x));
    return r;
}
__device__ __forceinline__ float rcpa(float x) {    // raw v_rcp_f32 (same rule)
    float r;
    asm("v_rcp_f32 %0, %1" : "=v"(r) : "v"(x));
    return r;
}

__device__ __forceinline__ unsigned pk2(float a, float b) {   // 2xf32 -> packed bf16x2 (RNE)
    union { __hip_bfloat162 h; unsigned u; } c;
    float2 t; t.x = a; t.y = b;
    c.h = __float22bfloat162_rn(t);
    return c.u;
}
__device__ __forceinline__ s16x8 cvt8(const float* p) {  // 8 fp32 -> bf16x8
    union { unsigned u[4]; s16x8 v; } r;
    r.u[0] = pk2(p[0], p[1]); r.u[1] = pk2(p[2], p[3]);
    r.u[2] = pk2(p[4], p[5]); r.u[3] = pk2(p[6], p[7]);
    return r.v;
}

// ---------------------------------------------------------------- kernel 0
// LN once per (b,l1,l2) row -> bf16 zn, row-major [131072][64]. Thread-per-row,
// identical summation order and packing to the in-ka LN (bit-identical).
__global__ __launch_bounds__(256, 2)
void k0_ln(const float* __restrict__ z, const float* __restrict__ ln_s,
           const float* __restrict__ ln_b, short* __restrict__ znG)
{
    const size_t row = (size_t)blockIdx.x * 256 + threadIdx.x;   // 0..131071
    float zn[64];
    const float4* zp4 = (const float4*)(z + row * 64);
    #pragma unroll
    for (int gq = 0; gq < 16; ++gq) {
        float4 v4 = zp4[gq];
        zn[gq * 4 + 0] = v4.x; zn[gq * 4 + 1] = v4.y;
        zn[gq * 4 + 2] = v4.z; zn[gq * 4 + 3] = v4.w;
    }
    float mu = 0.f;
    #pragma unroll
    for (int k = 0; k < 64; ++k) mu += zn[k];
    mu *= (1.f / 64.f);
    float va = 0.f;
    #pragma unroll
    for (int k = 0; k < 64; ++k) { float d = zn[k] - mu; va += d * d; }
    const float rs = rsqrtf(va * (1.f / 64.f) + 1e-5f);
    #pragma unroll
    for (int k = 0; k < 64; ++k) zn[k] = (zn[k] - mu) * rs * ln_s[k] + ln_b[k];
    union { unsigned u[32]; uint4 q[8]; } pk;
    #pragma unroll
    for (int k = 0; k < 32; ++k) pk.u[k] = pk2(zn[2 * k], zn[2 * k + 1]);
    uint4* dst = (uint4*)(znG + row * 64);
    #pragma unroll
    for (int i = 0; i < 8; ++i) dst[i] = pk.q[i];
}

// LDS map (shorts): KSH [256 pos][20 sh pad], VT [16 dh][264 pos-pad].
static constexpr int KSH = 0;          // 256*20 = 5120 sh
static constexpr int VT  = 5120;       // 16*264 = 4224 sh
static constexpr int LDS_EL = 9344;    // 18688 B

__global__ __launch_bounds__(256, 3)
void ka_fused(const short* __restrict__ znG, const float* __restrict__ Wq,
              const float* __restrict__ Wk, const float* __restrict__ Wv,
              const float* __restrict__ Wg, const float* __restrict__ bg,
              short* __restrict__ ws)
{
    __shared__ __align__(16) short lds[LDS_EL];
    const int tid = threadIdx.x, lane = tid & 63, w = tid >> 6;
    const int n16 = lane & 15, quad = lane >> 4;
    const int g = blockIdx.x, bl = g & 511, h = g >> 9;   // same-bl heads -> same XCD
    const int wsl_rows = w * 64;                   // wave's query rows within bl

    // ---- W head-slice frags (serve as A for Q/K/G-transposed, B for V) ----
    s16x8 bq[2], bk[2], bv[2], bgf[2];
    #pragma unroll
    for (int ks = 0; ks < 2; ++ks) {
        size_t off = (size_t)(h * 16 + n16) * 64 + ks * 32 + quad * 8;
        bq[ks] = cvt8(Wq + off);  bk[ks] = cvt8(Wk + off);
        bv[ks] = cvt8(Wv + off);  bgf[ks] = cvt8(Wg + off);
    }
    const float4 bg4 = *(const float4*)(bg + h * 16 + quad * 4);
    constexpr float QS  = 0.25f;                            // 1/sqrt(Dh); log2e at exp
    constexpr float L2E = 1.44269504088896340736f;

    float g4t[4][4];
    s16x4 qa4[4];                                  // Q^T B-frags, in-register
    #pragma unroll
    for (int t = 0; t < 4; ++t) {                  // projections for tile t
        // Direct global fragment loads: zn0 covers ch k=quad*8+u, zn1 k=32+...
        const short* zr = znG + ((size_t)bl * 256 + wsl_rows + t * 16 + n16) * 64
                          + quad * 8;
        s16x8 zn0 = *(const s16x8*)zr;
        s16x8 zn1 = *(const s16x8*)(zr + 32);
        f32x4 aq = {}, ak = {}, av = {}, ag = {};
        aq = MFMA16(bq[0], zn0, aq);  aq = MFMA16(bq[1], zn1, aq);   // Q^T
        ak = MFMA16(bk[0], zn0, ak);  ak = MFMA16(bk[1], zn1, ak);   // K^T
        ag = MFMA16(bgf[0], zn0, ag); ag = MFMA16(bgf[1], zn1, ag);  // G^T
        av = MFMA16(zn0, bv[0], av);  av = MFMA16(zn1, bv[1], av);   // V
        {   // Q^T (scaled) -> in-register B-frag: lane holds Q^T[dh=quad*4+r][i=n16]
            union { unsigned u[2]; s16x4 v; } q;
            q.u[0] = pk2(aq[0] * QS, aq[1] * QS);
            q.u[1] = pk2(aq[2] * QS, aq[3] * QS);
            qa4[t] = q.v;
        }
        {   // K^T -> KSH[pos][dh] (stride 20, conflict-free b64 frags)
            uint2 p = {pk2(ak[0], ak[1]), pk2(ak[2], ak[3])};
            *(uint2*)&lds[KSH + (wsl_rows + t * 16 + n16) * 20 + quad * 4] = p;
        }
        {   // V -> VT[dh][pos] (shared)
            uint2 p = {pk2(av[0], av[1]), pk2(av[2], av[3])};
            *(uint2*)&lds[VT + n16 * 264 + (wsl_rows + t * 16 + quad * 4)] = p;
        }
        #pragma unroll
        for (int r = 0; r < 4; ++r) {               // gate (pos=n16, dh=q*4+r)
            float x = ag[r] + bg4[r];               // VALU add absorbs MFMA hazard
            g4t[t][r] = rcpa(1.f + exp2a(x * -L2E)); // sigmoid via raw exp2/rcp
        }
    }
    __syncthreads();   // the ONLY barrier: KSH/VT visible

    // ---- attention, all 16x16x16: S^T = K@Q^T; P in-register; O^T = V^T@P^T;
    //      l = ones@P^T on the matrix pipe ----
    f32x4 o4[4], lacc[4];
    #pragma unroll
    for (int qt = 0; qt < 4; ++qt) { o4[qt] = {}; lacc[qt] = {}; }
    s16x4 ones4;                                    // bf16 1.0 x4
    {
        union { unsigned u[2]; s16x4 v; } c;
        c.u[0] = 0x3F803F80u; c.u[1] = 0x3F803F80u;
        ones4 = c.v;
    }
    const int kbase = KSH + n16 * 20 + quad * 4;    // + jt*320
    const int vbase = VT + n16 * 264 + quad * 4;    // + jt*16
    for (int ch = 0; ch < 8; ++ch) {                // 32 keys per chunk
        #pragma unroll
        for (int jtl = 0; jtl < 2; ++jtl) {
            const int jt = ch * 2 + jtl;
            // kf: A[m=key=n16][k=dh=quad*4+u]; vf: A[m=dh=n16][k=key=quad*4+u]
            s16x4 kf = *(const s16x4*)&lds[kbase + jt * 320];
            s16x4 vf = *(const s16x4*)&lds[vbase + jt * 16];
            #pragma unroll
            for (int qt = 0; qt < 4; ++qt) {
                f32x4 zc = {};
                f32x4 s = mfma16b(kf, qa4[qt], zc);  // S^T: reg r = P-row key=quad*4+r, col i=n16
                // v_mul (compiler VALU) absorbs the MFMA->read hazard, then the
                // asm v_exp reads a VALU result (hardware-interlocked).
                float e0 = exp2a(s[0] * L2E), e1 = exp2a(s[1] * L2E);
                float e2 = exp2a(s[2] * L2E), e3 = exp2a(s[3] * L2E);
                union { unsigned u[2]; s16x4 v; } pb;
                pb.u[0] = pk2(e0, e1); pb.u[1] = pk2(e2, e3);
                // pb IS the PV B-frag: B[k=key=quad*4+u][n=i=n16]
                o4[qt]   = mfma16b(vf, pb.v, o4[qt]);      // O^T: col=i, row=dh
                lacc[qt] = mfma16b(ones4, pb.v, lacc[qt]); // l[i], all rows
            }
        }
    }

    // ---- epilogue: gate, direct coalesced GO stores (l replicated: no shfl) ----
    #pragma unroll
    for (int qt = 0; qt < 4; ++qt) {
        // Two compiler VALU ops (add, mul) absorb the MFMA->asm hazard on lacc.
        const float l = (lacc[qt][0] + lacc[qt][1]) * 0.5f;
        const float inv = rcpa(l);
        float g0 = g4t[qt][0] * o4[qt][0] * inv;
        float g1 = g4t[qt][1] * o4[qt][1] * inv;
        float g2 = g4t[qt][2] * o4[qt][2] * inv;
        float g3 = g4t[qt][3] * o4[qt][3] * inv;
        uint2 p = {pk2(g0, g1), pk2(g2, g3)};
        short* dst = ws + (((size_t)h * 512 + bl) * 256 + wsl_rows + qt * 16 + n16) * 16
                     + quad * 4;
        *(uint2*)dst = p;
    }
}

// ---------------------------------------------------------------- kernel 3
// out = sum_h GO_h @ Wo_h^T + bo ; grid 1024 (bl=b&511 -> XCD bl%8, matching
// where ka wrote GO for this bl -> L2 hits), block 256, 32 rows/wave.
// __launch_bounds__(256,2): kernel needs ~85 VGPRs; the old (256,4) bound
// clamps the allocator to 64 (r7 evidence) -> likely silent scratch spill.
// Operand-swapped MFMA -> D col(lane&15)=row, D row(quad*4+r)=4 consecutive
// out cols -> f32x4 stores. Writes EVERY element of out (zn scratch overwritten).
__global__ __launch_bounds__(256, 2)
void k3_out(const short* __restrict__ ws, const float* __restrict__ Wo,
            const float* __restrict__ bo, float* __restrict__ out)
{
    const int tid = threadIdx.x, lane = tid & 63, w = tid >> 6;
    const int n16 = lane & 15, quad = lane >> 4;
    const short* GO = ws;
    const int bl = blockIdx.x & 511, half = blockIdx.x >> 9;
    const int rowloc = half * 128 + w * 32;

    s16x8 bfr[4][2];   // Wo[outd = nt*16+n16][ind = c*32 + quad*8 + u]
    #pragma unroll
    for (int nt = 0; nt < 4; ++nt)
        #pragma unroll
        for (int ks = 0; ks < 2; ++ks)
            bfr[nt][ks] = cvt8(Wo + (size_t)(nt * 16 + n16) * 64 + ks * 32 + quad * 8);

    f32x4 acc[2][4] = {};
    #pragma unroll
    for (int mt = 0; mt < 2; ++mt) {
        #pragma unroll
        for (int c = 0; c < 2; ++c) {
            int hp = c * 2 + (quad >> 1);
            const short* ap = &GO[(((size_t)hp * 512 + bl) * 256 + rowloc + mt * 16 + n16) * 16
                                  + (quad & 1) * 8];
            s16x8 a = *(const s16x8*)ap;
            #pragma unroll
            for (int nt = 0; nt < 4; ++nt)
                acc[mt][nt] = MFMA16(bfr[nt][c], a, acc[mt][nt]);   // swapped
        }
    }
    #pragma unroll
    for (int nt = 0; nt < 4; ++nt) {
        const float4 b4 = *(const float4*)(bo + nt * 16 + quad * 4);
        f32x4 b4v; b4v[0] = b4.x; b4v[1] = b4.y; b4v[2] = b4.z; b4v[3] = b4.w;
        #pragma unroll
        for (int mt = 0; mt < 2; ++mt) {
            f32x4 v = acc[mt][nt] + b4v;
            *(f32x4*)&out[((size_t)bl * 256 + rowloc + mt * 16 + n16) * 64
                          + nt * 16 + quad * 4] = v;
        }
    }
}

extern "C" void kernel_launch(void* const* d_in, const int* in_sizes, int n_in,
                              void* d_out, int out_size, void* d_ws, size_t ws_size,
                              hipStream_t stream) {
    const float* z  = (const float*)d_in[0];
    const float* ls = (const float*)d_in[1];
    const float* lb = (const float*)d_in[2];
    const float* Wq = (const float*)d_in[3];
    const float* Wk = (const float*)d_in[4];
    const float* Wv = (const float*)d_in[5];
    const float* Wg = (const float*)d_in[6];
    const float* bg = (const float*)d_in[7];
    const float* Wo = (const float*)d_in[8];
    const float* bo = (const float*)d_in[9];
    float* out = (float*)d_out;
    short* wsp = (short*)d_ws;
    // zn scratch = first 16.8 MB of out (33.5 MB); k3 overwrites all of out.
    short* znG = (short*)d_out;

    hipLaunchKernelGGL(k0_ln, dim3(512), dim3(256), 0, stream, z, ls, lb, znG);
    hipLaunchKernelGGL(ka_fused, dim3(2048), dim3(256), 0, stream,
                       znG, Wq, Wk, Wv, Wg, bg, wsp);
    hipLaunchKernelGGL(k3_out, dim3(1024), dim3(256), 0, stream, wsp, Wo, bo, out);
}

// Round 12
// 143.762 us; speedup vs baseline: 1.0918x; 1.0918x over previous
//
#include <hip/hip_runtime.h>
#include <hip/hip_bf16.h>
#include <math.h>

// TriangleAttention — round 18: FULL FUSION into one kernel. Pipeline math
// showed ~85-110 µs of residual (launch/harness/memset + k0 + k3) that ka
// polishing cannot touch; this round removes 2 launches, the zn global
// round-trip and the GO global round-trip entirely.
//   grid 512 = bl-slab; block 256 (4 waves, wave w owns query rows w*64..+64);
//   heads processed SEQUENTIALLY per block:
//     LN once per row (k0's redundancy win, now in-block) -> persistent znl LDS;
//     per head: proj (K^T->KSH, V->VT, Q^T/gate in-reg) -> sync -> attention
//     (16x16x16, P in-reg) -> epilogue: the gated normalized O^T fragment IS
//     the Wo-projection B-fragment (same identity family as r14) -> 16 MFMAs
//     accumulate out in registers -> sync -> next head.
//   Final: out = acc + bo, float4 stores. No ws, no k0, no k3.
// LDS 51.5 KB -> 2 blocks/CU = grid 512 fully resident. __launch_bounds__(256,2)
// -> 256-VGPR budget (est peak ~150, no spill possible).
// HAZARD RULES (r10-r14): inline asm never reads an MFMA dest directly — a
// compiler VALU op in between (s*L2E mul / ag+bg add / lacc add+mul) absorbs
// the wait-states. BAN LIST (r7-8): __builtin_amdgcn_exp2f/rcpf.
// CANARY: absmax exactly 0.0078125; WRITE ~34 MB (out only; >40 MB = spill).
// B=2, L=256, D=64, H=4, Dh=16.
//
// 16x16x32 layouts (verified r2-5):  A[m=lane&15][k=quad*8+u],
//   B[k=quad*8+u][n=lane&15], C/D: col=lane&15, row=quad*4+reg.
// 16x16x16 layouts (verified r14): A[m=lane&15][k=quad*4+u],
//   B[k=quad*4+u][n=lane&15], C/D identical to above.

typedef __attribute__((ext_vector_type(4))) float f32x4;
typedef __attribute__((ext_vector_type(8))) short s16x8;
typedef __attribute__((ext_vector_type(4))) short s16x4;

#define MFMA16(a, b, c) __builtin_amdgcn_mfma_f32_16x16x32_bf16((a), (b), (c), 0, 0, 0)

__device__ __forceinline__ f32x4 mfma16b(s16x4 a, s16x4 b, f32x4 c) {
#if __has_builtin(__builtin_amdgcn_mfma_f32_16x16x16bf16_1k)
    return __builtin_amdgcn_mfma_f32_16x16x16bf16_1k(a, b, c, 0, 0, 0);
#elif __has_builtin(__builtin_amdgcn_mfma_f32_16x16x16_bf16)
    return __builtin_amdgcn_mfma_f32_16x16x16_bf16(a, b, c, 0, 0, 0);
#else
    f32x4 d;
    asm volatile("s_nop 1\n\t"
                 "v_mfma_f32_16x16x16_bf16 %0, %1, %2, %3\n\t"
                 "s_nop 7\n\t"
                 "s_nop 7"
                 : "=v"(d) : "v"(a), "v"(b), "v"(c));
    return d;
#endif
}

__device__ __forceinline__ float exp2a(float x) {   // raw v_exp_f32 (input MUST
    float r;                                        // be VALU-produced, not MFMA)
    asm("v_exp_f32 %0, %1" : "=v"(r) : "v"(x));
    return r;
}
__device__ __forceinline__ float rcpa(float x) {    // raw v_rcp_f32 (same rule)
    float r;
    asm("v_rcp_f32 %0, %1" : "=v"(r) : "v"(x));
    return r;
}

__device__ __forceinline__ unsigned pk2(float a, float b) {   // 2xf32 -> packed bf16x2 (RNE)
    union { __hip_bfloat162 h; unsigned u; } c;
    float2 t; t.x = a; t.y = b;
    c.h = __float22bfloat162_rn(t);
    return c.u;
}
__device__ __forceinline__ s16x8 cvt8(const float* p) {  // 8 fp32 -> bf16x8
    union { unsigned u[4]; s16x8 v; } r;
    r.u[0] = pk2(p[0], p[1]); r.u[1] = pk2(p[2], p[3]);
    r.u[2] = pk2(p[4], p[5]); r.u[3] = pk2(p[6], p[7]);
    return r.v;
}
__device__ __forceinline__ s16x4 cvt4(const float* p) {  // 4 fp32 -> bf16x4
    union { unsigned u[2]; s16x4 v; } r;
    r.u[0] = pk2(p[0], p[1]); r.u[1] = pk2(p[2], p[3]);
    return r.v;
}

// LDS map (shorts).
//   ZNL: persistent LN'd rows, wave slice w*4096; row lr at
//        (lr>>4)*1024 + (lr&15)*64, gq-swizzled (r6-verified layout).
//   KSH [256 pos][20 sh pad] b64 frags; VT [16 dh][264 pos-pad]. Reused per head.
static constexpr int ZNL = 0;          // 4*4096 = 16384 sh
static constexpr int KSH = 16384;      // 256*20 = 5120 sh
static constexpr int VT  = 21504;      // 16*264 = 4224 sh
static constexpr int LDS_EL = 25728;   // 51456 B -> 2 blocks/CU (grid 512 resident)

__global__ __launch_bounds__(256, 2)
void ka_all(const float* __restrict__ z, const float* __restrict__ ln_s,
            const float* __restrict__ ln_b, const float* __restrict__ Wq,
            const float* __restrict__ Wk, const float* __restrict__ Wv,
            const float* __restrict__ Wg, const float* __restrict__ bg,
            const float* __restrict__ Wo, const float* __restrict__ bo,
            float* __restrict__ out)
{
    __shared__ __align__(16) short lds[LDS_EL];
    const int tid = threadIdx.x, lane = tid & 63, w = tid >> 6;
    const int n16 = lane & 15, quad = lane >> 4;
    const int bl = blockIdx.x;
    const int wsl = w * 4096;                      // wave's znl slice
    const int wrows = w * 64;                      // wave's query rows in slab

    // ---- LN once per row: thread = row (bl*256 + tid); swizzled store ----
    {
        float zn[64];
        const float4* zp4 = (const float4*)(z + ((size_t)bl * 256 + tid) * 64);
        #pragma unroll
        for (int gq = 0; gq < 16; ++gq) {
            float4 v4 = zp4[gq];
            zn[gq * 4 + 0] = v4.x; zn[gq * 4 + 1] = v4.y;
            zn[gq * 4 + 2] = v4.z; zn[gq * 4 + 3] = v4.w;
        }
        float mu = 0.f;
        #pragma unroll
        for (int k = 0; k < 64; ++k) mu += zn[k];
        mu *= (1.f / 64.f);
        float va = 0.f;
        #pragma unroll
        for (int k = 0; k < 64; ++k) { float d = zn[k] - mu; va += d * d; }
        const float rs = rsqrtf(va * (1.f / 64.f) + 1e-5f);
        #pragma unroll
        for (int k = 0; k < 64; ++k) zn[k] = (zn[k] - mu) * rs * ln_s[k] + ln_b[k];
        const int lr = lane;
        #pragma unroll
        for (int gq = 0; gq < 8; ++gq) {
            union { unsigned u[4]; s16x8 v; } pkv;
            pkv.u[0] = pk2(zn[gq * 8 + 0], zn[gq * 8 + 1]);
            pkv.u[1] = pk2(zn[gq * 8 + 2], zn[gq * 8 + 3]);
            pkv.u[2] = pk2(zn[gq * 8 + 4], zn[gq * 8 + 5]);
            pkv.u[3] = pk2(zn[gq * 8 + 6], zn[gq * 8 + 7]);
            *(s16x8*)&lds[ZNL + wsl + (lr >> 4) * 1024 + (lr & 15) * 64
                          + ((gq ^ (lr & 7)) * 8)] = pkv.v;
        }
    }
    // Projections read only this wave's own slice -> same-wave DS ordering
    // suffices (r12/r14-validated); no barrier here.

    constexpr float QS  = 0.25f;                            // 1/sqrt(Dh); log2e at exp
    constexpr float L2E = 1.44269504088896340736f;
    s16x4 ones4;                                            // bf16 1.0 x4
    {
        union { unsigned u[2]; s16x4 v; } c;
        c.u[0] = 0x3F803F80u; c.u[1] = 0x3F803F80u;
        ones4 = c.v;
    }

    f32x4 acc_out[4][4];                           // [qt][nt], persistent over heads
    #pragma unroll
    for (int qt = 0; qt < 4; ++qt)
        #pragma unroll
        for (int nt = 0; nt < 4; ++nt) acc_out[qt][nt] = {};

    for (int h = 0; h < 4; ++h) {
        // ---- W head-slice frags (A for Q/K/G-transposed, B for V) ----
        s16x8 bq[2], bk[2], bv[2], bgf[2];
        #pragma unroll
        for (int ks = 0; ks < 2; ++ks) {
            size_t off = (size_t)(h * 16 + n16) * 64 + ks * 32 + quad * 8;
            bq[ks] = cvt8(Wq + off);  bk[ks] = cvt8(Wk + off);
            bv[ks] = cvt8(Wv + off);  bgf[ks] = cvt8(Wg + off);
        }
        const float4 bg4 = *(const float4*)(bg + h * 16 + quad * 4);

        float g4t[4][4];
        s16x4 qa4[4];                              // Q^T B-frags, in-register
        #pragma unroll
        for (int t = 0; t < 4; ++t) {              // projections for tile t
            s16x8 zn0 = *(const s16x8*)&lds[ZNL + wsl + t * 1024 + n16 * 64
                                            + ((quad ^ (n16 & 7)) * 8)];
            s16x8 zn1 = *(const s16x8*)&lds[ZNL + wsl + t * 1024 + n16 * 64
                                            + (((4 + quad) ^ (n16 & 7)) * 8)];
            f32x4 aq = {}, ak = {}, av = {}, ag = {};
            aq = MFMA16(bq[0], zn0, aq);  aq = MFMA16(bq[1], zn1, aq);   // Q^T
            ak = MFMA16(bk[0], zn0, ak);  ak = MFMA16(bk[1], zn1, ak);   // K^T
            ag = MFMA16(bgf[0], zn0, ag); ag = MFMA16(bgf[1], zn1, ag);  // G^T
            av = MFMA16(zn0, bv[0], av);  av = MFMA16(zn1, bv[1], av);   // V
            {   // Q^T (scaled) -> in-register B-frag: Q^T[dh=quad*4+r][i=n16]
                union { unsigned u[2]; s16x4 v; } q;
                q.u[0] = pk2(aq[0] * QS, aq[1] * QS);
                q.u[1] = pk2(aq[2] * QS, aq[3] * QS);
                qa4[t] = q.v;
            }
            {   // K^T -> KSH[pos][dh] (stride 20, conflict-free b64 frags)
                uint2 p = {pk2(ak[0], ak[1]), pk2(ak[2], ak[3])};
                *(uint2*)&lds[KSH + (wrows + t * 16 + n16) * 20 + quad * 4] = p;
            }
            {   // V -> VT[dh][pos]
                uint2 p = {pk2(av[0], av[1]), pk2(av[2], av[3])};
                *(uint2*)&lds[VT + n16 * 264 + (wrows + t * 16 + quad * 4)] = p;
            }
            #pragma unroll
            for (int r = 0; r < 4; ++r) {           // gate (pos=n16, dh=q*4+r)
                float x = ag[r] + bg4[r];           // VALU add absorbs MFMA hazard
                g4t[t][r] = rcpa(1.f + exp2a(x * -L2E));
            }
        }
        __syncthreads();   // KSH/VT for head h visible to all waves

        // ---- attention (16x16x16): S^T = K@Q^T; P in-register; O^T = V^T@P^T;
        //      l = ones@P^T on the matrix pipe ----
        f32x4 o4[4], lacc[4];
        #pragma unroll
        for (int qt = 0; qt < 4; ++qt) { o4[qt] = {}; lacc[qt] = {}; }
        const int kbase = KSH + n16 * 20 + quad * 4;    // + jt*320
        const int vbase = VT + n16 * 264 + quad * 4;    // + jt*16
        for (int ch = 0; ch < 8; ++ch) {                // 32 keys per chunk
            #pragma unroll
            for (int jtl = 0; jtl < 2; ++jtl) {
                const int jt = ch * 2 + jtl;
                s16x4 kf = *(const s16x4*)&lds[kbase + jt * 320];
                s16x4 vf = *(const s16x4*)&lds[vbase + jt * 16];
                #pragma unroll
                for (int qt = 0; qt < 4; ++qt) {
                    f32x4 zc = {};
                    f32x4 s = mfma16b(kf, qa4[qt], zc);  // S^T: reg r = key q*4+r, col i=n16
                    // v_mul absorbs the MFMA->asm hazard.
                    float e0 = exp2a(s[0] * L2E), e1 = exp2a(s[1] * L2E);
                    float e2 = exp2a(s[2] * L2E), e3 = exp2a(s[3] * L2E);
                    union { unsigned u[2]; s16x4 v; } pb;
                    pb.u[0] = pk2(e0, e1); pb.u[1] = pk2(e2, e3);
                    o4[qt]   = mfma16b(vf, pb.v, o4[qt]);      // O^T: col=i, row=dh
                    lacc[qt] = mfma16b(ones4, pb.v, lacc[qt]); // l[i], all rows
                }
            }
        }

        // ---- per-head epilogue: gate+normalize -> bf16 -> Wo MFMA accumulate.
        // The gated O^T fragment (col=i=n16, row=dh=quad*4+r) IS the B-frag
        // B[k=dh][n=i] for out_tile = Wo_slice @ GO^T.
        s16x4 goB[4];
        #pragma unroll
        for (int qt = 0; qt < 4; ++qt) {
            const float l = (lacc[qt][0] + lacc[qt][1]) * 0.5f;  // VALU ops absorb hazard
            const float inv = rcpa(l);
            float g0 = g4t[qt][0] * o4[qt][0] * inv;
            float g1 = g4t[qt][1] * o4[qt][1] * inv;
            float g2 = g4t[qt][2] * o4[qt][2] * inv;
            float g3 = g4t[qt][3] * o4[qt][3] * inv;
            union { unsigned u[2]; s16x4 v; } pb;
            pb.u[0] = pk2(g0, g1); pb.u[1] = pk2(g2, g3);
            goB[qt] = pb.v;
        }
        #pragma unroll
        for (int nt = 0; nt < 4; ++nt) {
            // Wo A-frag: A[m=outd local=n16][k=dh=quad*4+u] for tile nt, head h
            s16x4 wof = cvt4(Wo + (size_t)(nt * 16 + n16) * 64 + h * 16 + quad * 4);
            #pragma unroll
            for (int qt = 0; qt < 4; ++qt)
                acc_out[qt][nt] = mfma16b(wof, goB[qt], acc_out[qt][nt]);
        }
        __syncthreads();   // protect KSH/VT before next head's proj writes
    }

    // ---- final store: out = acc + bo. D: col=i=n16 (query row),
    // row=quad*4+r = out-dim within tile nt -> float4 stores. ----
    #pragma unroll
    for (int nt = 0; nt < 4; ++nt) {
        const float4 b4 = *(const float4*)(bo + nt * 16 + quad * 4);
        f32x4 b4v; b4v[0] = b4.x; b4v[1] = b4.y; b4v[2] = b4.z; b4v[3] = b4.w;
        #pragma unroll
        for (int qt = 0; qt < 4; ++qt) {
            f32x4 v = acc_out[qt][nt] + b4v;   // VALU add absorbs MFMA->store path
            *(f32x4*)&out[((size_t)bl * 256 + wrows + qt * 16 + n16) * 64
                          + nt * 16 + quad * 4] = v;
        }
    }
}

extern "C" void kernel_launch(void* const* d_in, const int* in_sizes, int n_in,
                              void* d_out, int out_size, void* d_ws, size_t ws_size,
                              hipStream_t stream) {
    const float* z  = (const float*)d_in[0];
    const float* ls = (const float*)d_in[1];
    const float* lb = (const float*)d_in[2];
    const float* Wq = (const float*)d_in[3];
    const float* Wk = (const float*)d_in[4];
    const float* Wv = (const float*)d_in[5];
    const float* Wg = (const float*)d_in[6];
    const float* bg = (const float*)d_in[7];
    const float* Wo = (const float*)d_in[8];
    const float* bo = (const float*)d_in[9];
    float* out = (float*)d_out;

    hipLaunchKernelGGL(ka_all, dim3(512), dim3(256), 0, stream,
                       z, ls, lb, Wq, Wk, Wv, Wg, bg, Wo, bo, out);
}